// Round 2
// baseline (322.338 us; speedup 1.0000x reference)
//
#include <hip/hip_runtime.h>

// NeRF raw2outputs, fp32 in/out (per reference dtypes), fp32 math.
// One wave (64 lanes) per ray; lane l owns samples {l, l+64, l+128}.
// Exclusive cumprod via shfl_up scan per 64-chunk, chained over 3 chunks.

#define NS 192
#define INF_DIST 1e10f

__global__ __launch_bounds__(256) void nerf_render(
    const float4* __restrict__ raw,    // [N, S] float4 {r,g,b,sigma}
    const float*  __restrict__ z_vals, // [N, S]
    const float*  __restrict__ rays_d, // [N, 3]
    float* __restrict__ out,           // rgb(3N)|disp(N)|acc(N)|weights(192N)|depth(N)
    int N)
{
    const int lane = threadIdx.x & 63;
    const int ray  = (blockIdx.x << 2) + (threadIdx.x >> 6);  // 4 waves/block
    if (ray >= N) return;

    // ray-direction norm (same cache lines for all lanes -> broadcast)
    float dxv = rays_d[ray * 3 + 0];
    float dyv = rays_d[ray * 3 + 1];
    float dzv = rays_d[ray * 3 + 2];
    float norm = sqrtf(dxv * dxv + dyv * dyv + dzv * dzv);

    // z chunks: coalesced 4B/lane
    const float* zr = z_vals + (size_t)ray * NS;
    float zchunks[3];
    zchunks[0] = zr[lane];
    zchunks[1] = zr[lane + 64];
    zchunks[2] = zr[lane + 128];

    // raw chunks: 16B/lane float4, fully coalesced (1 KiB/wave/chunk)
    const float4* rr = raw + (size_t)ray * NS;
    float4 rchunks[3];
    rchunks[0] = rr[lane];
    rchunks[1] = rr[lane + 64];
    rchunks[2] = rr[lane + 128];

    float* w_out = out + (size_t)N * 5 + (size_t)ray * NS;

    float chain = 1.0f;  // product of (1-alpha+eps) over previous chunks
    float racc = 0.f, gacc = 0.f, bacc = 0.f, dacc = 0.f, aacc = 0.f;

    #pragma unroll
    for (int k = 0; k < 3; ++k) {
        float4 rv = rchunks[k];
        float z = zchunks[k];

        // dist = z[s+1]-z[s]; chunk boundary from lane 0 of next chunk;
        // very last sample = INF_DIST.
        float zn = __shfl_down(z, 1);
        if (k < 2) {
            float zfirst = __shfl(zchunks[k + 1], 0);
            if (lane == 63) zn = zfirst;
        }
        float dist = (k == 2 && lane == 63) ? INF_DIST : (zn - z);
        dist *= norm;

        float sigma = fmaxf(rv.w, 0.0f);
        float alpha = 1.0f - __expf(-sigma * dist);
        float v = 1.0f - alpha + 1e-10f;

        // inclusive product scan across 64 lanes (6 shfl_up steps)
        float p = v;
        #pragma unroll
        for (int off = 1; off < 64; off <<= 1) {
            float t = __shfl_up(p, off);
            if (lane >= off) p *= t;
        }
        float ex = __shfl_up(p, 1);                 // exclusive scan
        float T  = chain * ((lane == 0) ? 1.0f : ex);
        float w  = alpha * T;
        chain   *= __shfl(p, 63);                   // chunk total product

        racc += w * (1.0f / (1.0f + __expf(-rv.x)));
        gacc += w * (1.0f / (1.0f + __expf(-rv.y)));
        bacc += w * (1.0f / (1.0f + __expf(-rv.z)));
        dacc += w * z;
        aacc += w;

        w_out[(k << 6) + lane] = w;                 // coalesced 4B/lane store
    }

    // butterfly reduction over 64 lanes
    #pragma unroll
    for (int off = 32; off >= 1; off >>= 1) {
        racc += __shfl_xor(racc, off);
        gacc += __shfl_xor(gacc, off);
        bacc += __shfl_xor(bacc, off);
        dacc += __shfl_xor(dacc, off);
        aacc += __shfl_xor(aacc, off);
    }

    if (lane == 0) {
        float acc   = aacc;
        float depth = dacc;
        if (acc <= 1e-10f) depth = INF_DIST;
        float disp = 1.0f / fmaxf(1e-10f, depth / acc);  // acc==0 -> inf -> 0, matches np
        out[(size_t)ray * 3 + 0] = racc;
        out[(size_t)ray * 3 + 1] = gacc;
        out[(size_t)ray * 3 + 2] = bacc;
        out[(size_t)N * 3 + ray]   = disp;
        out[(size_t)N * 4 + ray]   = acc;
        out[(size_t)N * 197 + ray] = depth;
    }
}

extern "C" void kernel_launch(void* const* d_in, const int* in_sizes, int n_in,
                              void* d_out, int out_size, void* d_ws, size_t ws_size,
                              hipStream_t stream) {
    const float4* raw    = (const float4*)d_in[0];
    const float*  z_vals = (const float*)d_in[1];
    const float*  rays_d = (const float*)d_in[2];
    float* out = (float*)d_out;
    int N = in_sizes[2] / 3;                 // rays_d is [N,3]
    int blocks = (N + 3) / 4;                // 4 rays (waves) per 256-thread block
    hipLaunchKernelGGL(nerf_render, dim3(blocks), dim3(256), 0, stream,
                       raw, z_vals, rays_d, out, N);
}

// Round 4
// 301.196 us; speedup vs baseline: 1.0702x; 1.0702x over previous
//
#include <hip/hip_runtime.h>

// NeRF raw2outputs, fp32 in/out, fp32 math.
// One wave (64 lanes) per ray; lane l owns samples {l, l+64, l+128}.
// Exclusive cumprod via shfl_up scan per 64-chunk, chained over 3 chunks.
// Single-pass stream -> nontemporal loads/stores (nt) to avoid cache pollution.

#define NS 192
#define INF_DIST 1e10f

typedef float floatx4 __attribute__((ext_vector_type(4)));  // native vec for nt builtins

__global__ __launch_bounds__(256) void nerf_render(
    const floatx4* __restrict__ raw,   // [N, S] {r,g,b,sigma}
    const float*  __restrict__ z_vals, // [N, S]
    const float*  __restrict__ rays_d, // [N, 3]
    float* __restrict__ out,           // rgb(3N)|disp(N)|acc(N)|weights(192N)|depth(N)
    int N)
{
    const int lane = threadIdx.x & 63;
    const int ray  = (blockIdx.x << 2) + (threadIdx.x >> 6);  // 4 waves/block
    if (ray >= N) return;

    // ray-direction norm (broadcast within wave; rays_d is tiny -> keep cached)
    float dxv = rays_d[ray * 3 + 0];
    float dyv = rays_d[ray * 3 + 1];
    float dzv = rays_d[ray * 3 + 2];
    float norm = sqrtf(dxv * dxv + dyv * dyv + dzv * dzv);

    // z chunks: coalesced 4B/lane, streaming
    const float* zr = z_vals + (size_t)ray * NS;
    float zchunks[3];
    zchunks[0] = __builtin_nontemporal_load(zr + lane);
    zchunks[1] = __builtin_nontemporal_load(zr + lane + 64);
    zchunks[2] = __builtin_nontemporal_load(zr + lane + 128);

    // raw chunks: 16B/lane, fully coalesced (1 KiB/wave/chunk), streaming
    const floatx4* rr = raw + (size_t)ray * NS;
    floatx4 rchunks[3];
    rchunks[0] = __builtin_nontemporal_load(rr + lane);
    rchunks[1] = __builtin_nontemporal_load(rr + lane + 64);
    rchunks[2] = __builtin_nontemporal_load(rr + lane + 128);

    float* w_out = out + (size_t)N * 5 + (size_t)ray * NS;

    float chain = 1.0f;  // product of (1-alpha+eps) over previous chunks
    float racc = 0.f, gacc = 0.f, bacc = 0.f, dacc = 0.f, aacc = 0.f;

    #pragma unroll
    for (int k = 0; k < 3; ++k) {
        floatx4 rv = rchunks[k];
        float z = zchunks[k];

        // dist = z[s+1]-z[s]; chunk boundary from lane 0 of next chunk;
        // very last sample = INF_DIST.
        float zn = __shfl_down(z, 1);
        if (k < 2) {
            float zfirst = __shfl(zchunks[k + 1], 0);
            if (lane == 63) zn = zfirst;
        }
        float dist = (k == 2 && lane == 63) ? INF_DIST : (zn - z);
        dist *= norm;

        float sigma = fmaxf(rv.w, 0.0f);
        float alpha = 1.0f - __expf(-sigma * dist);
        float v = 1.0f - alpha + 1e-10f;

        // inclusive product scan across 64 lanes (6 shfl_up steps)
        float p = v;
        #pragma unroll
        for (int off = 1; off < 64; off <<= 1) {
            float t = __shfl_up(p, off);
            if (lane >= off) p *= t;
        }
        float ex = __shfl_up(p, 1);                 // exclusive scan
        float T  = chain * ((lane == 0) ? 1.0f : ex);
        float w  = alpha * T;
        chain   *= __shfl(p, 63);                   // chunk total product

        racc += w * (1.0f / (1.0f + __expf(-rv.x)));
        gacc += w * (1.0f / (1.0f + __expf(-rv.y)));
        bacc += w * (1.0f / (1.0f + __expf(-rv.z)));
        dacc += w * z;
        aacc += w;

        __builtin_nontemporal_store(w, w_out + (k << 6) + lane);  // streaming store
    }

    // butterfly reduction over 64 lanes
    #pragma unroll
    for (int off = 32; off >= 1; off >>= 1) {
        racc += __shfl_xor(racc, off);
        gacc += __shfl_xor(gacc, off);
        bacc += __shfl_xor(bacc, off);
        dacc += __shfl_xor(dacc, off);
        aacc += __shfl_xor(aacc, off);
    }

    if (lane == 0) {
        float acc   = aacc;
        float depth = dacc;
        if (acc <= 1e-10f) depth = INF_DIST;
        float disp = 1.0f / fmaxf(1e-10f, depth / acc);  // acc==0 -> inf -> 0, matches np
        out[(size_t)ray * 3 + 0] = racc;
        out[(size_t)ray * 3 + 1] = gacc;
        out[(size_t)ray * 3 + 2] = bacc;
        out[(size_t)N * 3 + ray]   = disp;
        out[(size_t)N * 4 + ray]   = acc;
        out[(size_t)N * 197 + ray] = depth;
    }
}

extern "C" void kernel_launch(void* const* d_in, const int* in_sizes, int n_in,
                              void* d_out, int out_size, void* d_ws, size_t ws_size,
                              hipStream_t stream) {
    const floatx4* raw   = (const floatx4*)d_in[0];
    const float*  z_vals = (const float*)d_in[1];
    const float*  rays_d = (const float*)d_in[2];
    float* out = (float*)d_out;
    int N = in_sizes[2] / 3;                 // rays_d is [N,3]
    int blocks = (N + 3) / 4;                // 4 rays (waves) per 256-thread block
    hipLaunchKernelGGL(nerf_render, dim3(blocks), dim3(256), 0, stream,
                       raw, z_vals, rays_d, out, N);
}